// Round 1
// baseline (561.731 us; speedup 1.0000x reference)
//
#include <hip/hip_runtime.h>
#include <stdint.h>

#define B_ 8
#define D_ 4096
#define H_ 32
#define HD_ 128
#define KV_ 512
#define PAST_ 8191
#define SCALE_ 0.08838834764831845f  // 128^-0.5

// workspace layout (float offsets)
#define OFF_QP   0u          // q partials   [64][8][32][512]
#define OFF_CP   8388608u    // c partials   [64][8][512]
#define OFF_QABS 8650752u    // q_abs        [8][32][512]
#define OFF_CNEW 8781824u    // c_new        [8][512]
#define OFF_ML   8785920u    // m,l          [8][64][64]
#define OFF_CTXP 8818688u    // ctx partials [8][64][32][512]
#define OFF_CTX2 17207296u   // ctx2         [8][4096]
// total 17240064 floats = 69 MB

typedef float f32x4 __attribute__((ext_vector_type(4)));
typedef float f32x2 __attribute__((ext_vector_type(2)));
typedef short s16x8 __attribute__((ext_vector_type(8)));
typedef short s16x4 __attribute__((ext_vector_type(4)));

__device__ __forceinline__ unsigned short f2bf(float f) {
    unsigned u = __float_as_uint(f);
    u = (u + 0x7FFFu + ((u >> 16) & 1u)) >> 16;
    return (unsigned short)u;
}
__device__ __forceinline__ float bf2f(unsigned short s) {
    return __uint_as_float(((unsigned)s) << 16);
}

// ---------------- Kernel A: partial q_abs / c_new GEMV, no atomics
// grid (33, 64): x = h (32 == compress), y = d-chunk of 64 rows. 128 threads.
// 2112 blocks * 2 waves = 4224 waves (~16/CU) with 16-deep f32x4 load staging:
// this is the 276 MB stream that was latency-bound at ~1 wave/SIMD before.
__global__ __launch_bounds__(128) void k_qabs(const float* __restrict__ x,
                                              const float* __restrict__ aqk,
                                              const float* __restrict__ wc,
                                              float* __restrict__ ws) {
    const int h = blockIdx.x;
    const int dc = blockIdx.y;
    const int t = threadIdx.x;
    // x transposed: xT[row][b] so per-row broadcast is 2 ds_read_b128
    alignas(16) __shared__ float xT[64][8];
    {
        const int b = t >> 4, g = t & 15;
        const f32x4 v = *(const f32x4*)(x + (size_t)b * D_ + dc * 64 + g * 4);
#pragma unroll
        for (int e = 0; e < 4; ++e) xT[g * 4 + e][b] = v[e];
    }
    __syncthreads();
    const float* A = ((h < H_) ? (aqk + (size_t)h * D_ * KV_) : wc)
                   + ((size_t)dc * 64) * KV_ + t * 4;

    f32x4 acc[B_];
#pragma unroll
    for (int b = 0; b < B_; ++b) acc[b] = (f32x4){0.f, 0.f, 0.f, 0.f};

    for (int r0 = 0; r0 < 64; r0 += 16) {
        f32x4 a[16];
#pragma unroll
        for (int u = 0; u < 16; ++u)
            a[u] = *(const f32x4*)(A + (size_t)(r0 + u) * KV_);
#pragma unroll
        for (int u = 0; u < 16; ++u) {
            const f32x4 xa = *(const f32x4*)&xT[r0 + u][0];
            const f32x4 xb = *(const f32x4*)&xT[r0 + u][4];
            acc[0] += xa[0] * a[u];
            acc[1] += xa[1] * a[u];
            acc[2] += xa[2] * a[u];
            acc[3] += xa[3] * a[u];
            acc[4] += xb[0] * a[u];
            acc[5] += xb[1] * a[u];
            acc[6] += xb[2] * a[u];
            acc[7] += xb[3] * a[u];
        }
    }
#pragma unroll
    for (int b = 0; b < B_; ++b) {
        float* dst = (h < H_)
            ? (ws + OFF_QP + (size_t)dc * 131072u + (size_t)(b * H_ + h) * KV_ + t * 4)
            : (ws + OFF_CP + (size_t)dc * 4096u + (size_t)b * KV_ + t * 4);
        *(f32x4*)dst = acc[b];
    }
}

// ---------------- Kernel A2: reduce 64 partial slices
// grid 264: blocks 0..255 = (b,h) q rows; 256..263 = c_new rows. 512 threads:
// slice dim split across thread-halves -> 32 KB in flight per block.
__global__ __launch_bounds__(512) void k_qred(float* __restrict__ ws) {
    const int bx = blockIdx.x;
    const int t = threadIdx.x;
    const int pg = t >> 8, tt = t & 255;
    alignas(16) __shared__ float part[2][512];

    const float* src;
    size_t stride;
    float* dst;
    if (bx < 256) {
        src = ws + OFF_QP + (size_t)pg * 32u * 131072u + (size_t)bx * KV_ + 2 * tt;
        stride = 131072u;
        dst = ws + OFF_QABS + (size_t)bx * KV_;
    } else {
        const int b = bx - 256;
        src = ws + OFF_CP + (size_t)pg * 32u * 4096u + (size_t)b * KV_ + 2 * tt;
        stride = 4096u;
        dst = ws + OFF_CNEW + (size_t)b * KV_;
    }
    f32x2 s = {0.f, 0.f};
#pragma unroll 8
    for (int p = 0; p < 32; ++p) {
        const f32x2 v = *(const f32x2*)(src + (size_t)p * stride);
        s[0] += v[0]; s[1] += v[1];
    }
    *(f32x2*)&part[pg][2 * tt] = s;
    __syncthreads();
    if (t < 256) {
        const f32x2 p0 = *(const f32x2*)&part[0][2 * t];
        const f32x2 p1 = *(const f32x2*)&part[1][2 * t];
        *(f32x2*)(dst + 2 * t) = (f32x2){p0[0] + p1[0], p0[1] + p1[1]};
    }
}

// ---------------- Kernel B: split-KV flash attention over compressed cache
// grid 512: block = (b, sc) ; chunk = 128 s, sub-chunks of 16 s
__global__ __launch_bounds__(256, 2) void k_attn(const float* __restrict__ past_c,
                                                 float* __restrict__ ws) {
    const int bx = blockIdx.x;
    const int b = bx >> 6, sc = bx & 63;
    const int t = threadIdx.x;
    const int w = t >> 6, lane = t & 63, quad = lane >> 4, ln = lane & 15;
    const int ni = w & 1, kh = w >> 1;

    alignas(16) __shared__ unsigned short ch[16 * 520];   // c hi, row-major [s][k]
    alignas(16) __shared__ unsigned short cl[16 * 520];   // c lo
    alignas(16) __shared__ unsigned short cT[512 * 20];   // c hi transposed [k][s^swz]
    alignas(16) __shared__ float Sp[2 * 16 * 33];         // score partials [khalf][s][h]
    alignas(16) __shared__ unsigned short P[32 * 20];     // attn weights bf16 [h][s]
    __shared__ float alpha[32];

    // q fragments (pre-scaled by SCALE, split hi/lo) held in registers
    s16x8 qh[8], ql[8];
    {
        const float* qp = ws + OFF_QABS + (size_t)(b * H_ + ni * 16 + ln) * KV_ + kh * 256 + quad * 8;
#pragma unroll
        for (int st = 0; st < 8; ++st) {
            const f32x4 v0 = *(const f32x4*)(qp + st * 32);
            const f32x4 v1 = *(const f32x4*)(qp + st * 32 + 4);
#pragma unroll
            for (int i = 0; i < 8; ++i) {
                const float xv = ((i < 4) ? v0[i] : v1[i - 4]) * SCALE_;
                const unsigned short hi = f2bf(xv);
                qh[st][i] = (short)hi;
                ql[st][i] = (short)f2bf(xv - bf2f(hi));
            }
        }
    }

    f32x4 cacc[16];
#pragma unroll
    for (int i = 0; i < 16; ++i) cacc[i] = (f32x4){0.f, 0.f, 0.f, 0.f};
    float m_run = -1e30f, l_run = 0.f;

    for (int sub = 0; sub < 8; ++sub) {
        const int s0 = sc * 128 + sub * 16;
        // ---- stage 16 c rows: lane owns 4-consecutive-col chunks (bank-balanced)
        {
            const int r = t >> 4, m = t & 15;
            const int sg = s0 + r;
            const float* src = (sg == PAST_) ? (ws + OFF_CNEW + (size_t)b * KV_)
                                             : (past_c + ((size_t)b * PAST_ + sg) * KV_);
#pragma unroll
            for (int i = 0; i < 8; ++i) {
                const int k = m * 4 + i * 64;
                const f32x4 v = *(const f32x4*)(src + k);
                s16x4 hi4, lo4;
#pragma unroll
                for (int e = 0; e < 4; ++e) {
                    const unsigned short hh = f2bf(v[e]);
                    hi4[e] = (short)hh;
                    lo4[e] = (short)f2bf(v[e] - bf2f(hh));
                    const int kk = k + e;
                    cT[kk * 20 + (r ^ ((((kk) >> 4) & 3) << 2))] = hh;  // swizzled
                }
                *(s16x4*)&ch[r * 520 + k] = hi4;
                *(s16x4*)&cl[r * 520 + k] = lo4;
            }
        }
        __syncthreads();
        // ---- scores^T: D[s][h] = sum_k c[s][k] * q[h][k], split precision
        {
            f32x4 sacc = {0.f, 0.f, 0.f, 0.f};
#pragma unroll
            for (int st = 0; st < 8; ++st) {
                const int ko = kh * 256 + st * 32 + quad * 8;
                const s16x8 ah = *(const s16x8*)&ch[ln * 520 + ko];
                const s16x8 al = *(const s16x8*)&cl[ln * 520 + ko];
                sacc = __builtin_amdgcn_mfma_f32_16x16x32_bf16(ah, qh[st], sacc, 0, 0, 0);
                sacc = __builtin_amdgcn_mfma_f32_16x16x32_bf16(ah, ql[st], sacc, 0, 0, 0);
                sacc = __builtin_amdgcn_mfma_f32_16x16x32_bf16(al, qh[st], sacc, 0, 0, 0);
            }
#pragma unroll
            for (int r = 0; r < 4; ++r)
                Sp[kh * 528 + (quad * 4 + r) * 33 + ni * 16 + ln] = sacc[r];
        }
        __syncthreads();
        // ---- online softmax (thread t = head h)
        if (t < 32) {
            const int h = t;
            float sv[16];
            float msub = -1e30f;
#pragma unroll
            for (int s = 0; s < 16; ++s) {
                sv[s] = Sp[s * 33 + h] + Sp[528 + s * 33 + h];
                msub = fmaxf(msub, sv[s]);
            }
            const float m_new = fmaxf(m_run, msub);
            const float al_ = __expf(m_run - m_new);
            float lsum = 0.f;
#pragma unroll
            for (int s = 0; s < 16; s += 2) {
                const float p0 = __expf(sv[s] - m_new);
                const float p1 = __expf(sv[s + 1] - m_new);
                lsum += p0 + p1;
                const unsigned pk = (unsigned)f2bf(p0) | ((unsigned)f2bf(p1) << 16);
                *(unsigned*)&P[h * 20 + s] = pk;
            }
            l_run = l_run * al_ + lsum;
            m_run = m_new;
            alpha[h] = al_;
        }
        __syncthreads();
        // ---- ctx^T accumulate: D[k][h] += sum_s cT[k][s] * P[h][s]
        {
            const float av = alpha[ni * 16 + ln];
            const s16x4 bp = *(const s16x4*)&P[(ni * 16 + ln) * 20 + quad * 4];
#pragma unroll
            for (int ti = 0; ti < 16; ++ti) {
                const int krow = (kh * 16 + ti) * 16 + ln;
                const int sg2 = (quad ^ ((krow >> 4) & 3)) << 2;   // un-swizzle
                const s16x4 ac = *(const s16x4*)&cT[krow * 20 + sg2];
                f32x4 cc = cacc[ti];
                cc[0] *= av; cc[1] *= av; cc[2] *= av; cc[3] *= av;
                cacc[ti] = __builtin_amdgcn_mfma_f32_16x16x16bf16_1k(ac, bp, cc, 0, 0, 0);
            }
        }
        __syncthreads();
    }
    // ---- write partial ctx (unnormalized, base m_run) + (m, l)
    {
        float* cp = ws + OFF_CTXP + ((size_t)(b * 64 + sc) * H_ + (ni * 16 + ln)) * KV_;
#pragma unroll
        for (int ti = 0; ti < 16; ++ti) {
            const int k0 = (kh * 16 + ti) * 16 + quad * 4;
            *(f32x4*)(cp + k0) = cacc[ti];
        }
    }
    if (t < 32) {
        float* mp = ws + OFF_ML + (size_t)(b * 64 + sc) * 64;
        mp[t] = m_run;
        mp[32 + t] = l_run;
    }
}

// ---------------- Kernel C: fused combine + v_up. grid 256 = (b,h), 512 threads
__global__ __launch_bounds__(512) void k_cv(const float* __restrict__ wv,
                                            float* __restrict__ ws) {
    const int b = blockIdx.x >> 5, h = blockIdx.x & 31;
    const int t = threadIdx.x;
    __shared__ float ml[64], ll[64], wgt[64];
    alignas(16) __shared__ float cx[512];
    alignas(16) __shared__ float cpart[2][512];
    alignas(16) __shared__ float red[16][128];
    if (t < 64) {
        const float* mp = ws + OFF_ML + (size_t)(b * 64 + t) * 64;
        ml[t] = mp[h];
        ll[t] = mp[32 + h];
    }
    __syncthreads();
    float M = -1e30f;
    for (int s = 0; s < 64; ++s) M = fmaxf(M, ml[s]);
    if (t < 64) wgt[t] = __expf(ml[t] - M);
    __syncthreads();
    float L = 0.f;
    for (int s = 0; s < 64; ++s) L += ll[s] * wgt[s];
    const float invL = 1.f / L;
    // combine phase: s-chunks split across thread-halves
    const int half = t >> 8, tt = t & 255;
    f32x2 acc = {0.f, 0.f};
#pragma unroll 8
    for (int s = half; s < 64; s += 2) {
        const float f = wgt[s];
        const f32x2 v = *(const f32x2*)(ws + OFF_CTXP + ((size_t)(b * 64 + s) * H_ + h) * KV_ + 2 * tt);
        acc[0] += f * v[0];
        acc[1] += f * v[1];
    }
    *(f32x2*)&cpart[half][2 * tt] = acc;
    __syncthreads();
    if (t < 256) {
        const f32x2 p0 = *(const f32x2*)&cpart[0][2 * t];
        const f32x2 p1 = *(const f32x2*)&cpart[1][2 * t];
        *(f32x2*)&cx[2 * t] = (f32x2){(p0[0] + p1[0]) * invL, (p0[1] + p1[1]) * invL};
    }
    __syncthreads();
    // v_up: out[hd] = sum_k cx[k] * wv[k][h*128+hd], 16 k-rows in parallel
    const int r = t >> 5, c = (t & 31) * 4;
    f32x4 a4 = {0.f, 0.f, 0.f, 0.f};
#pragma unroll 4
    for (int kb = 0; kb < 32; ++kb) {
        const int k = kb * 16 + r;
        const f32x4 w4 = *(const f32x4*)(wv + (size_t)k * (H_ * HD_) + h * HD_ + c);
        a4 += cx[k] * w4;
    }
    *(f32x4*)&red[r][c] = a4;
    __syncthreads();
    if (t < 128) {
        float s = 0.f;
#pragma unroll
        for (int rr = 0; rr < 16; ++rr) s += red[rr][t];
        ws[OFF_CTX2 + (size_t)b * D_ + h * HD_ + t] = s;
    }
}

// ---------------- Kernel E: out[b][d] += sum_j ctx2[b][j] * w_o[j][d]
// grid (16 d-chunks, 16 j-chunks)
__global__ __launch_bounds__(256) void k_out(const float* __restrict__ wo,
                                             const float* __restrict__ ws,
                                             float* __restrict__ out) {
    const int dc = blockIdx.x, jc = blockIdx.y;
    const int t = threadIdx.x;
    alignas(16) __shared__ float c2[B_][256];
#pragma unroll
    for (int i = 0; i < 8; ++i) {
        const int e = t + i * 256;
        const int bb = e >> 8, jj = e & 255;
        c2[bb][jj] = ws[OFF_CTX2 + (size_t)bb * D_ + jc * 256 + jj];
    }
    __syncthreads();
    const int d = dc * 256 + t;
    float acc[B_] = {};
    for (int j = 0; j < 256; j += 8) {
        float wreg[8];
#pragma unroll
        for (int u = 0; u < 8; ++u)
            wreg[u] = wo[(size_t)(jc * 256 + j + u) * D_ + d];
#pragma unroll
        for (int b = 0; b < B_; ++b) {
            const f32x4 c0 = *(const f32x4*)&c2[b][j];
            const f32x4 c1 = *(const f32x4*)&c2[b][j + 4];
            acc[b] += c0[0] * wreg[0] + c0[1] * wreg[1] + c0[2] * wreg[2] + c0[3] * wreg[3]
                    + c1[0] * wreg[4] + c1[1] * wreg[5] + c1[2] * wreg[6] + c1[3] * wreg[7];
        }
    }
#pragma unroll
    for (int b = 0; b < B_; ++b)
        atomicAdd(&out[b * D_ + d], acc[b]);
}

extern "C" void kernel_launch(void* const* d_in, const int* in_sizes, int n_in,
                              void* d_out, int out_size, void* d_ws, size_t ws_size,
                              hipStream_t stream) {
    const float* x      = (const float*)d_in[0];
    const float* past_c = (const float*)d_in[1];
    const float* aqk    = (const float*)d_in[2];
    const float* wc     = (const float*)d_in[3];
    const float* wv     = (const float*)d_in[4];
    const float* wo     = (const float*)d_in[5];
    float* out = (float*)d_out;
    float* ws  = (float*)d_ws;

    hipMemsetAsync(d_out, 0, (size_t)out_size * sizeof(float), stream);

    k_qabs<<<dim3(33, 64), 128, 0, stream>>>(x, aqk, wc, ws);
    k_qred<<<dim3(264), 512, 0, stream>>>(ws);
    k_attn<<<dim3(512), 256, 0, stream>>>(past_c, ws);
    k_cv<<<dim3(256), 512, 0, stream>>>(wv, ws);
    k_out<<<dim3(16, 16), 256, 0, stream>>>(wo, ws, out);
}

// Round 2
// 545.358 us; speedup vs baseline: 1.0300x; 1.0300x over previous
//
#include <hip/hip_runtime.h>
#include <stdint.h>

#define B_ 8
#define D_ 4096
#define H_ 32
#define HD_ 128
#define KV_ 512
#define PAST_ 8191
#define SCALE_ 0.08838834764831845f  // 128^-0.5

// workspace layout (float offsets)
#define OFF_QP   0u          // q partials   [16][8][32][512]
#define OFF_CP   2097152u    // c partials   [16][8][512]
#define OFF_QABS 2162688u    // q_abs        [8][32][512]
#define OFF_CNEW 2293760u    // c_new        [8][512]
#define OFF_ML   2297856u    // m,l          [8][64][64]
#define OFF_CTXP 2330624u    // ctx partials [8][64][32][512]
#define OFF_CTX2 10719232u   // ctx2         [8][4096]
// total 10752000 floats = 43 MB

typedef float f32x4 __attribute__((ext_vector_type(4)));
typedef float f32x2 __attribute__((ext_vector_type(2)));
typedef short s16x8 __attribute__((ext_vector_type(8)));
typedef short s16x4 __attribute__((ext_vector_type(4)));

__device__ __forceinline__ unsigned short f2bf(float f) {
    unsigned u = __float_as_uint(f);
    u = (u + 0x7FFFu + ((u >> 16) & 1u)) >> 16;
    return (unsigned short)u;
}
__device__ __forceinline__ float bf2f(unsigned short s) {
    return __uint_as_float(((unsigned)s) << 16);
}

// ---------------- Kernel A: partial q_abs / c_new GEMV, no atomics
// grid (33, 16): x = h (32 == compress), y = d-chunk of 256 rows. 128 threads.
// 528 blocks * 2 waves, 16-deep f32x4 staging (16 KB in flight per block).
__global__ __launch_bounds__(128) void k_qabs(const float* __restrict__ x,
                                              const float* __restrict__ aqk,
                                              const float* __restrict__ wc,
                                              float* __restrict__ ws) {
    const int h = blockIdx.x;
    const int dc = blockIdx.y;
    const int t = threadIdx.x;
    // x transposed: xT[row][b] so per-row broadcast is 2 ds_read_b128
    alignas(16) __shared__ float xT[256][8];
#pragma unroll
    for (int j = 0; j < 4; ++j) {
        const int i = t + j * 128;          // 0..511 = (b, 64 f32x4-groups)
        const int b = i >> 6, g = i & 63;
        const f32x4 v = *(const f32x4*)(x + (size_t)b * D_ + dc * 256 + g * 4);
#pragma unroll
        for (int e = 0; e < 4; ++e) xT[g * 4 + e][b] = v[e];
    }
    __syncthreads();
    const float* A = ((h < H_) ? (aqk + (size_t)h * D_ * KV_) : wc)
                   + ((size_t)dc * 256) * KV_ + t * 4;

    f32x4 acc[B_];
#pragma unroll
    for (int b = 0; b < B_; ++b) acc[b] = (f32x4){0.f, 0.f, 0.f, 0.f};

    for (int r0 = 0; r0 < 256; r0 += 16) {
        f32x4 a[16];
#pragma unroll
        for (int u = 0; u < 16; ++u)
            a[u] = *(const f32x4*)(A + (size_t)(r0 + u) * KV_);
#pragma unroll
        for (int u = 0; u < 16; ++u) {
            const f32x4 xa = *(const f32x4*)&xT[r0 + u][0];
            const f32x4 xb = *(const f32x4*)&xT[r0 + u][4];
            acc[0] += xa[0] * a[u];
            acc[1] += xa[1] * a[u];
            acc[2] += xa[2] * a[u];
            acc[3] += xa[3] * a[u];
            acc[4] += xb[0] * a[u];
            acc[5] += xb[1] * a[u];
            acc[6] += xb[2] * a[u];
            acc[7] += xb[3] * a[u];
        }
    }
#pragma unroll
    for (int b = 0; b < B_; ++b) {
        float* dst = (h < H_)
            ? (ws + OFF_QP + (size_t)dc * 131072u + (size_t)(b * H_ + h) * KV_ + t * 4)
            : (ws + OFF_CP + (size_t)dc * 4096u + (size_t)b * KV_ + t * 4);
        *(f32x4*)dst = acc[b];
    }
}

// ---------------- Kernel A2: reduce 16 partial slices
// grid 264: blocks 0..255 = (b,h) q rows; 256..263 = c_new rows. 512 threads:
// slice dim split across thread-halves.
__global__ __launch_bounds__(512) void k_qred(float* __restrict__ ws) {
    const int bx = blockIdx.x;
    const int t = threadIdx.x;
    const int pg = t >> 8, tt = t & 255;
    alignas(16) __shared__ float part[2][512];

    const float* src;
    size_t stride;
    float* dst;
    if (bx < 256) {
        src = ws + OFF_QP + (size_t)pg * 8u * 131072u + (size_t)bx * KV_ + 2 * tt;
        stride = 131072u;
        dst = ws + OFF_QABS + (size_t)bx * KV_;
    } else {
        const int b = bx - 256;
        src = ws + OFF_CP + (size_t)pg * 8u * 4096u + (size_t)b * KV_ + 2 * tt;
        stride = 4096u;
        dst = ws + OFF_CNEW + (size_t)b * KV_;
    }
    f32x2 s = {0.f, 0.f};
#pragma unroll
    for (int p = 0; p < 8; ++p) {
        const f32x2 v = *(const f32x2*)(src + (size_t)p * stride);
        s[0] += v[0]; s[1] += v[1];
    }
    *(f32x2*)&part[pg][2 * tt] = s;
    __syncthreads();
    if (t < 256) {
        const f32x2 p0 = *(const f32x2*)&part[0][2 * t];
        const f32x2 p1 = *(const f32x2*)&part[1][2 * t];
        *(f32x2*)(dst + 2 * t) = (f32x2){p0[0] + p1[0], p0[1] + p1[1]};
    }
}

// ---------------- Kernel B: split-KV flash attention over compressed cache
// grid 512: block = (b, sc) ; chunk = 128 s, sub-chunks of 16 s.
// Staging loads for sub+1 are issued right after the staging barrier of sub,
// so HBM latency hides under scores/softmax/ctx instead of being exposed 8x.
__global__ __launch_bounds__(256, 2) void k_attn(const float* __restrict__ past_c,
                                                 float* __restrict__ ws) {
    const int bx = blockIdx.x;
    const int b = bx >> 6, sc = bx & 63;
    const int t = threadIdx.x;
    const int w = t >> 6, lane = t & 63, quad = lane >> 4, ln = lane & 15;
    const int ni = w & 1, kh = w >> 1;

    alignas(16) __shared__ unsigned short ch[16 * 520];   // c hi, row-major [s][k]
    alignas(16) __shared__ unsigned short cl[16 * 520];   // c lo
    alignas(16) __shared__ unsigned short cT[512 * 20];   // c hi transposed [k][s^swz]
    alignas(16) __shared__ float Sp[2 * 16 * 33];         // score partials [khalf][s][h]
    alignas(16) __shared__ unsigned short P[32 * 20];     // attn weights bf16 [h][s]
    __shared__ float alpha[32];

    // q fragments (pre-scaled by SCALE, split hi/lo) held in registers
    s16x8 qh[8], ql[8];
    {
        const float* qp = ws + OFF_QABS + (size_t)(b * H_ + ni * 16 + ln) * KV_ + kh * 256 + quad * 8;
#pragma unroll
        for (int st = 0; st < 8; ++st) {
            const f32x4 v0 = *(const f32x4*)(qp + st * 32);
            const f32x4 v1 = *(const f32x4*)(qp + st * 32 + 4);
#pragma unroll
            for (int i = 0; i < 8; ++i) {
                const float xv = ((i < 4) ? v0[i] : v1[i - 4]) * SCALE_;
                const unsigned short hi = f2bf(xv);
                qh[st][i] = (short)hi;
                ql[st][i] = (short)f2bf(xv - bf2f(hi));
            }
        }
    }

    f32x4 cacc[16];
#pragma unroll
    for (int i = 0; i < 16; ++i) cacc[i] = (f32x4){0.f, 0.f, 0.f, 0.f};
    float m_run = -1e30f, l_run = 0.f;

    const int r_st = t >> 4, m_st = t & 15;

    // prefetch sub 0's 16 c rows into registers
    f32x4 pre[8];
    {
        const int sg = sc * 128 + r_st;
        const float* src = (sg == PAST_) ? (ws + OFF_CNEW + (size_t)b * KV_)
                                         : (past_c + ((size_t)b * PAST_ + sg) * KV_);
#pragma unroll
        for (int i = 0; i < 8; ++i)
            pre[i] = *(const f32x4*)(src + m_st * 4 + i * 64);
    }

    for (int sub = 0; sub < 8; ++sub) {
        // ---- convert prefetched rows + write LDS (hi/lo split + swizzled cT)
        {
#pragma unroll
            for (int i = 0; i < 8; ++i) {
                const int k = m_st * 4 + i * 64;
                const f32x4 v = pre[i];
                s16x4 hi4, lo4;
#pragma unroll
                for (int e = 0; e < 4; ++e) {
                    const unsigned short hh = f2bf(v[e]);
                    hi4[e] = (short)hh;
                    lo4[e] = (short)f2bf(v[e] - bf2f(hh));
                    const int kk = k + e;
                    cT[kk * 20 + (r_st ^ ((((kk) >> 4) & 3) << 2))] = hh;  // swizzled
                }
                *(s16x4*)&ch[r_st * 520 + k] = hi4;
                *(s16x4*)&cl[r_st * 520 + k] = lo4;
            }
        }
        __syncthreads();
        // ---- issue next sub's staging loads (regs only; LDS still in use)
        if (sub < 7) {
            const int sg = sc * 128 + (sub + 1) * 16 + r_st;
            const float* src = (sg == PAST_) ? (ws + OFF_CNEW + (size_t)b * KV_)
                                             : (past_c + ((size_t)b * PAST_ + sg) * KV_);
#pragma unroll
            for (int i = 0; i < 8; ++i)
                pre[i] = *(const f32x4*)(src + m_st * 4 + i * 64);
        }
        // ---- scores^T: D[s][h] = sum_k c[s][k] * q[h][k], split precision
        {
            f32x4 sacc = {0.f, 0.f, 0.f, 0.f};
#pragma unroll
            for (int st = 0; st < 8; ++st) {
                const int ko = kh * 256 + st * 32 + quad * 8;
                const s16x8 ah = *(const s16x8*)&ch[ln * 520 + ko];
                const s16x8 al = *(const s16x8*)&cl[ln * 520 + ko];
                sacc = __builtin_amdgcn_mfma_f32_16x16x32_bf16(ah, qh[st], sacc, 0, 0, 0);
                sacc = __builtin_amdgcn_mfma_f32_16x16x32_bf16(ah, ql[st], sacc, 0, 0, 0);
                sacc = __builtin_amdgcn_mfma_f32_16x16x32_bf16(al, qh[st], sacc, 0, 0, 0);
            }
#pragma unroll
            for (int r = 0; r < 4; ++r)
                Sp[kh * 528 + (quad * 4 + r) * 33 + ni * 16 + ln] = sacc[r];
        }
        __syncthreads();
        // ---- online softmax (thread t = head h)
        if (t < 32) {
            const int h = t;
            float sv[16];
            float msub = -1e30f;
#pragma unroll
            for (int s = 0; s < 16; ++s) {
                sv[s] = Sp[s * 33 + h] + Sp[528 + s * 33 + h];
                msub = fmaxf(msub, sv[s]);
            }
            const float m_new = fmaxf(m_run, msub);
            const float al_ = __expf(m_run - m_new);
            float lsum = 0.f;
#pragma unroll
            for (int s = 0; s < 16; s += 2) {
                const float p0 = __expf(sv[s] - m_new);
                const float p1 = __expf(sv[s + 1] - m_new);
                lsum += p0 + p1;
                const unsigned pk = (unsigned)f2bf(p0) | ((unsigned)f2bf(p1) << 16);
                *(unsigned*)&P[h * 20 + s] = pk;
            }
            l_run = l_run * al_ + lsum;
            m_run = m_new;
            alpha[h] = al_;
        }
        __syncthreads();
        // ---- ctx^T accumulate: D[k][h] += sum_s cT[k][s] * P[h][s]
        {
            const float av = alpha[ni * 16 + ln];
            const s16x4 bp = *(const s16x4*)&P[(ni * 16 + ln) * 20 + quad * 4];
#pragma unroll
            for (int ti = 0; ti < 16; ++ti) {
                const int krow = (kh * 16 + ti) * 16 + ln;
                const int sg2 = (quad ^ ((krow >> 4) & 3)) << 2;   // un-swizzle
                const s16x4 ac = *(const s16x4*)&cT[krow * 20 + sg2];
                f32x4 cc = cacc[ti];
                cc[0] *= av; cc[1] *= av; cc[2] *= av; cc[3] *= av;
                cacc[ti] = __builtin_amdgcn_mfma_f32_16x16x16bf16_1k(ac, bp, cc, 0, 0, 0);
            }
        }
        __syncthreads();
    }
    // ---- write partial ctx (unnormalized, base m_run) + (m, l)
    {
        float* cp = ws + OFF_CTXP + ((size_t)(b * 64 + sc) * H_ + (ni * 16 + ln)) * KV_;
#pragma unroll
        for (int ti = 0; ti < 16; ++ti) {
            const int k0 = (kh * 16 + ti) * 16 + quad * 4;
            *(f32x4*)(cp + k0) = cacc[ti];
        }
    }
    if (t < 32) {
        float* mp = ws + OFF_ML + (size_t)(b * 64 + sc) * 64;
        mp[t] = m_run;
        mp[32 + t] = l_run;
    }
}

// ---------------- Kernel C: fused combine + v_up. grid 256 = (b,h), 512 threads
__global__ __launch_bounds__(512) void k_cv(const float* __restrict__ wv,
                                            float* __restrict__ ws) {
    const int b = blockIdx.x >> 5, h = blockIdx.x & 31;
    const int t = threadIdx.x;
    __shared__ float ml[64], ll[64], wgt[64];
    alignas(16) __shared__ float cx[512];
    alignas(16) __shared__ float cpart[2][512];
    alignas(16) __shared__ float red[16][128];
    if (t < 64) {
        const float* mp = ws + OFF_ML + (size_t)(b * 64 + t) * 64;
        ml[t] = mp[h];
        ll[t] = mp[32 + h];
    }
    __syncthreads();
    float M = -1e30f;
    for (int s = 0; s < 64; ++s) M = fmaxf(M, ml[s]);
    if (t < 64) wgt[t] = __expf(ml[t] - M);
    __syncthreads();
    float L = 0.f;
    for (int s = 0; s < 64; ++s) L += ll[s] * wgt[s];
    const float invL = 1.f / L;
    // combine phase: s-chunks split across thread-halves
    const int half = t >> 8, tt = t & 255;
    f32x2 acc = {0.f, 0.f};
#pragma unroll 8
    for (int s = half; s < 64; s += 2) {
        const float f = wgt[s];
        const f32x2 v = *(const f32x2*)(ws + OFF_CTXP + ((size_t)(b * 64 + s) * H_ + h) * KV_ + 2 * tt);
        acc[0] += f * v[0];
        acc[1] += f * v[1];
    }
    *(f32x2*)&cpart[half][2 * tt] = acc;
    __syncthreads();
    if (t < 256) {
        const f32x2 p0 = *(const f32x2*)&cpart[0][2 * t];
        const f32x2 p1 = *(const f32x2*)&cpart[1][2 * t];
        *(f32x2*)&cx[2 * t] = (f32x2){(p0[0] + p1[0]) * invL, (p0[1] + p1[1]) * invL};
    }
    __syncthreads();
    // v_up: out[hd] = sum_k cx[k] * wv[k][h*128+hd], 16 k-rows in parallel
    const int r = t >> 5, c = (t & 31) * 4;
    f32x4 a4 = {0.f, 0.f, 0.f, 0.f};
#pragma unroll 4
    for (int kb = 0; kb < 32; ++kb) {
        const int k = kb * 16 + r;
        const f32x4 w4 = *(const f32x4*)(wv + (size_t)k * (H_ * HD_) + h * HD_ + c);
        a4 += cx[k] * w4;
    }
    *(f32x4*)&red[r][c] = a4;
    __syncthreads();
    if (t < 128) {
        float s = 0.f;
#pragma unroll
        for (int rr = 0; rr < 16; ++rr) s += red[rr][t];
        ws[OFF_CTX2 + (size_t)b * D_ + h * HD_ + t] = s;
    }
}

// ---------------- Kernel E: out[b][d] += sum_j ctx2[b][j] * w_o[j][d]
// grid (16 d-chunks, 16 j-chunks)
__global__ __launch_bounds__(256) void k_out(const float* __restrict__ wo,
                                             const float* __restrict__ ws,
                                             float* __restrict__ out) {
    const int dc = blockIdx.x, jc = blockIdx.y;
    const int t = threadIdx.x;
    alignas(16) __shared__ float c2[B_][256];
#pragma unroll
    for (int i = 0; i < 8; ++i) {
        const int e = t + i * 256;
        const int bb = e >> 8, jj = e & 255;
        c2[bb][jj] = ws[OFF_CTX2 + (size_t)bb * D_ + jc * 256 + jj];
    }
    __syncthreads();
    const int d = dc * 256 + t;
    float acc[B_] = {};
    for (int j = 0; j < 256; j += 8) {
        float wreg[8];
#pragma unroll
        for (int u = 0; u < 8; ++u)
            wreg[u] = wo[(size_t)(jc * 256 + j + u) * D_ + d];
#pragma unroll
        for (int b = 0; b < B_; ++b) {
            const f32x4 c0 = *(const f32x4*)&c2[b][j];
            const f32x4 c1 = *(const f32x4*)&c2[b][j + 4];
            acc[b] += c0[0] * wreg[0] + c0[1] * wreg[1] + c0[2] * wreg[2] + c0[3] * wreg[3]
                    + c1[0] * wreg[4] + c1[1] * wreg[5] + c1[2] * wreg[6] + c1[3] * wreg[7];
        }
    }
#pragma unroll
    for (int b = 0; b < B_; ++b)
        atomicAdd(&out[b * D_ + d], acc[b]);
}

extern "C" void kernel_launch(void* const* d_in, const int* in_sizes, int n_in,
                              void* d_out, int out_size, void* d_ws, size_t ws_size,
                              hipStream_t stream) {
    const float* x      = (const float*)d_in[0];
    const float* past_c = (const float*)d_in[1];
    const float* aqk    = (const float*)d_in[2];
    const float* wc     = (const float*)d_in[3];
    const float* wv     = (const float*)d_in[4];
    const float* wo     = (const float*)d_in[5];
    float* out = (float*)d_out;
    float* ws  = (float*)d_ws;

    hipMemsetAsync(d_out, 0, (size_t)out_size * sizeof(float), stream);

    k_qabs<<<dim3(33, 16), 128, 0, stream>>>(x, aqk, wc, ws);
    k_qred<<<dim3(264), 512, 0, stream>>>(ws);
    k_attn<<<dim3(512), 256, 0, stream>>>(past_c, ws);
    k_cv<<<dim3(256), 512, 0, stream>>>(wv, ws);
    k_out<<<dim3(16, 16), 256, 0, stream>>>(wo, ws, out);
}